// Round 10
// baseline (647.605 us; speedup 1.0000x reference)
//
#include <hip/hip_runtime.h>
#include <hip/hip_bf16.h>
#include <math.h>

typedef __attribute__((ext_vector_type(8))) short short8;
typedef __attribute__((ext_vector_type(4))) float floatx4;
typedef unsigned short u16;

typedef __attribute__((address_space(1))) const void* gas_ptr;
typedef __attribute__((address_space(3))) void* las_ptr;

__device__ __forceinline__ float bf2f(u16 h) {
  union { unsigned u; float f; } v; v.u = ((unsigned)h) << 16; return v.f;
}
__device__ __forceinline__ u16 f2bf(float f) {
  union { float f; unsigned u; } v; v.f = f;
  unsigned r = v.u + 0x7FFFu + ((v.u >> 16) & 1u);
  return (u16)(r >> 16);
}
__device__ __forceinline__ float ldf_dyn(const void* p, size_t i, bool f32) {
  return f32 ? ((const float*)p)[i] : bf2f(((const u16*)p)[i]);
}
__device__ __forceinline__ short8 load8_dyn(const void* p, size_t idx, bool f32) {
  if (f32) {
    const float* f = (const float*)p;
    float4 a = *(const float4*)(f + idx);
    float4 b = *(const float4*)(f + idx + 4);
    short8 r;
    r[0] = (short)f2bf(a.x); r[1] = (short)f2bf(a.y);
    r[2] = (short)f2bf(a.z); r[3] = (short)f2bf(a.w);
    r[4] = (short)f2bf(b.x); r[5] = (short)f2bf(b.y);
    r[6] = (short)f2bf(b.z); r[7] = (short)f2bf(b.w);
    return r;
  }
  return *(const short8*)((const u16*)p + idx);
}
__device__ __forceinline__ void gl_lds16(const u16* g, u16* l) {
  __builtin_amdgcn_global_load_lds((gas_ptr)g, (las_ptr)l, 16, 0, 0);
}

// ---------------------------------------------------------------------------
__global__ void probe_dtype_kernel(const void* hidden, int* flag) {
  __shared__ int cnt;
  if (threadIdx.x == 0) cnt = 0;
  __syncthreads();
  const u16* h = (const u16*)hidden;
  int local = 0;
  for (int i = threadIdx.x; i < 8192; i += 256) {
    u16 u = h[i];
    int e = (u >> 7) & 0xFF;
    if ((e >= 64 && e <= 160) || (u & 0x7FFF) == 0) local++;
  }
  atomicAdd(&cnt, local);
  __syncthreads();
  if (threadIdx.x == 0) *flag = (cnt < 7700) ? 1 : 0;
}

// ---------------------------------------------------------------------------
// Only copies when input is f32 (bf16 input is consumed in place by gemm8p).
__global__ __launch_bounds__(256) void convert_dyn_kernel(
    const void* __restrict__ src, u16* __restrict__ dst, size_t n,
    const int* __restrict__ flagp)
{
  if (*flagp == 0) return;  // bf16: gemm8p reads src directly
  size_t i = ((size_t)blockIdx.x * 256 + threadIdx.x) * 8;
  if (i < n) *(short8*)(dst + i) = load8_dyn(src, i, true);
}

// ---------------------------------------------------------------------------
__global__ __launch_bounds__(256) void transpose_dyn_kernel(
    const void* __restrict__ src, u16* __restrict__ dst, int R, int C,
    const int* __restrict__ flagp)
{
  const bool f32 = (*flagp != 0);
  const int c0 = blockIdx.x * 64, r0 = blockIdx.y * 64;
  __shared__ __attribute__((aligned(16))) u16 T[64][72];
  const int tid = threadIdx.x;
#pragma unroll
  for (int i = 0; i < 2; i++) {
    int t = tid + i * 256;
    int r = t >> 3, cc = (t & 7) << 3;
    *(short8*)(&T[r][cc]) = load8_dyn(src, (size_t)(r0 + r) * C + c0 + cc, f32);
  }
  __syncthreads();
#pragma unroll
  for (int i = 0; i < 2; i++) {
    int t = tid + i * 256;
    int cr = t >> 3, rc = (t & 7) << 3;
    __attribute__((aligned(16))) u16 tmp[8];
#pragma unroll
    for (int j = 0; j < 8; j++) tmp[j] = T[rc + j][cr];
    *(short8*)(dst + (size_t)(c0 + cr) * R + r0 + rc) = *(const short8*)tmp;
  }
}

// ---------------------------------------------------------------------------
// Shared scheduling primitives for the 8-phase GEMMs.
// Swizzle f(r) = r&7: conflict-free ds_read_b128 (r5: 0 conflicts).
// SAFETY INVARIANTS:
//  - vmcnt is PER-WAVE; every VMW(n) gating a staged region is followed by
//    BAR() BEFORE any ds_read of that region; regions re-staged only strictly
//    after their last-read phase.
//  - OCCUPANCY/REGISTER NOTE (r9 insight): grids are exactly <=1 block/CU
//    (256 and 224 blocks on 256 CUs), so __launch_bounds__(512,1) raises the
//    arch-VGPR cap 128->256 at zero real occupancy cost. This legalizes the
//    r6 dual fa0/fa1 cross-phase lookahead that spilled under (512,2)
//    (WRITE_SIZE tripwire: must stay ~32 MB).
//  - r6 schedule is HW-verified correct (r6 run passed absmax).
// ---------------------------------------------------------------------------
#define BAR() __builtin_amdgcn_s_barrier()
#define SCB() __builtin_amdgcn_sched_barrier(0)
#define LGKM0() do { asm volatile("s_waitcnt lgkmcnt(0)" ::: "memory"); SCB(); } while (0)
#define LGKMC(n) do { asm volatile("s_waitcnt lgkmcnt(" #n ")" ::: "memory"); SCB(); } while (0)
#define VMW(n) do { asm volatile("s_waitcnt vmcnt(" #n ")" ::: "memory"); SCB(); } while (0)
#define PRIO1() __builtin_amdgcn_s_setprio(1)
#define PRIO0() do { __builtin_amdgcn_s_setprio(0); SCB(); } while (0)

// ------------------------- 256x256 tile (QKV GEMM) -------------------------
#define STG_AU(s, u, t) \
  gl_lds16(pa + (size_t)((u) * 64) * K + (size_t)(t) * 64, \
           ldsw + (s) * 32768 + (u) * 4096)
#define STG_BU(s, u, t) \
  gl_lds16(pb + (size_t)((u) * 64) * K + (size_t)(t) * 64, \
           ldsw + (s) * 32768 + 16384 + (u) * 4096)

#define RD_FA(A, s, miH) do { \
  _Pragma("unroll") \
  for (int m2 = 0; m2 < 4; m2++) { \
    const u16* _r = LDS + (s) * 32768 + wm * 8192 + (miH) * 4096 + m2 * 1024 + lane15 * 64; \
    A[m2][0] = *(const short8*)(_r + colA0); \
    A[m2][1] = *(const short8*)(_r + colA1); \
  } \
} while (0)
#define RD_FB(s, niH) do { \
  _Pragma("unroll") \
  for (int n2 = 0; n2 < 2; n2++) { \
    const u16* _r = LDS + (s) * 32768 + 16384 + wn * 4096 + (niH) * 2048 + n2 * 1024 + lane15 * 64; \
    fb[niH][n2][0] = *(const short8*)(_r + colA0); \
    fb[niH][n2][1] = *(const short8*)(_r + colA1); \
  } \
} while (0)
#define MFMA_Q(A, miH, niH) do { \
  PRIO1(); \
  _Pragma("unroll") \
  for (int m2 = 0; m2 < 4; m2++) \
    _Pragma("unroll") \
    for (int n2 = 0; n2 < 2; n2++) { \
      acc[(miH) * 4 + m2][(niH) * 2 + n2] = __builtin_amdgcn_mfma_f32_16x16x32_bf16( \
          A[m2][0], fb[niH][n2][0], acc[(miH) * 4 + m2][(niH) * 2 + n2], 0, 0, 0); \
      acc[(miH) * 4 + m2][(niH) * 2 + n2] = __builtin_amdgcn_mfma_f32_16x16x32_bf16( \
          A[m2][1], fb[niH][n2][1], acc[(miH) * 4 + m2][(niH) * 2 + n2], 0, 0, 0); \
    } \
  PRIO0(); \
} while (0)

__global__ __launch_bounds__(512, 1) void gemm8p_kernel(
    const void* __restrict__ Araw, const u16* __restrict__ Ahb,
    const u16* __restrict__ BT, u16* __restrict__ C,
    int M, int N, int K, const int* __restrict__ flagp)
{
  __shared__ __attribute__((aligned(16))) u16 LDS[65536];  // 128 KiB
  const int tid = threadIdx.x;
  const int wave = tid >> 6, lane = tid & 63;
  const int lane15 = lane & 15, quad = lane >> 4;
  const int wm = wave >> 2, wn = wave & 3;
  const int m0 = blockIdx.y * 256, n0 = blockIdx.x * 256;

  const u16* Abase = (*flagp != 0) ? Ahb : (const u16*)Araw;

  const int rloc = wave * 8 + (lane >> 3);
  const int sxor = lane >> 3;
  const int csw = ((lane & 7) ^ sxor) * 8;  // u16 units
  const u16* pa = Abase + (size_t)(m0 + rloc) * K + csw;
  const u16* pb = BT + (size_t)(n0 + rloc) * K + csw;
  u16* ldsw = LDS + wave * 512;

  const int swz = lane15 & 7;
  const int colA0 = (quad ^ swz) * 8;
  const int colA1 = ((4 + quad) ^ swz) * 8;

  floatx4 acc[8][4];
#pragma unroll
  for (int i = 0; i < 8; i++)
#pragma unroll
    for (int j = 0; j < 4; j++) acc[i][j] = (floatx4){0.f, 0.f, 0.f, 0.f};
  short8 fa0[4][2], fa1[4][2], fb[2][2][2];

  const int NT = K >> 6, NI = NT >> 1;

  // prologue: slot0 <- tile0 (8 loads), slot1 <- tile1 (A u0,u2 + B, 6 loads)
  STG_AU(0, 0, 0); STG_AU(0, 2, 0);
  STG_BU(0, 0, 0); STG_BU(0, 1, 0);
  STG_BU(0, 2, 0); STG_BU(0, 3, 0);
  STG_AU(0, 1, 0); STG_AU(0, 3, 0);
  STG_AU(1, 0, 1); STG_AU(1, 2, 1);
  STG_BU(1, 0, 1); STG_BU(1, 1, 1);
  STG_BU(1, 2, 1); STG_BU(1, 3, 1);
  VMW(8);           // this wave's tile0 A-u02 + B done
  BAR();            // -> all waves' slices landed

  for (int i = 0; i < NI - 1; i++) {
    const int t1 = 2 * i + 1, t2 = 2 * i + 2, t3 = 2 * i + 3;
    // P1: slot0 Q(0,0); self fa0+fb0 (12 reads) then fb1 lookahead (4)
    RD_FA(fa0, 0, 0); RD_FB(0, 0);
    SCB();
    STG_AU(1, 1, t1); STG_AU(1, 3, t1);
    RD_FB(0, 1);
    BAR(); LGKMC(4); MFMA_Q(fa0, 0, 0); VMW(8); BAR();   // A-s0-u13(t) landed
    // P2: slot0 Q(0,1); fa1 lookahead (8) overlaps MFMA
    RD_FA(fa1, 0, 1);
    SCB();
    STG_AU(0, 0, t2); STG_AU(0, 2, t2);
    BAR(); LGKMC(8); MFMA_Q(fa0, 0, 1); BAR();
    // P3: slot0 Q(1,1) [fa1 drained here, issued 1 phase ago]
    STG_BU(0, 0, t2); STG_BU(0, 1, t2);
    BAR(); LGKM0(); MFMA_Q(fa1, 1, 1); BAR();
    // P4: slot0 Q(1,0) regs-only
    STG_BU(0, 2, t2); STG_BU(0, 3, t2);
    BAR(); MFMA_Q(fa1, 1, 0); VMW(8); BAR();             // slot1 A-u02+B(t1) landed
    // P5: slot1 Q(0,0)
    RD_FA(fa0, 1, 0); RD_FB(1, 0);
    SCB();
    STG_AU(0, 1, t2); STG_AU(0, 3, t2);
    RD_FB(1, 1);
    BAR(); LGKMC(4); MFMA_Q(fa0, 0, 0); VMW(8); BAR();   // A-s1-u13(t1) landed
    // P6: slot1 Q(0,1)
    RD_FA(fa1, 1, 1);
    SCB();
    STG_AU(1, 0, t3); STG_AU(1, 2, t3);
    BAR(); LGKMC(8); MFMA_Q(fa0, 0, 1); BAR();
    // P7: slot1 Q(1,1)
    STG_BU(1, 0, t3); STG_BU(1, 1, t3);
    BAR(); LGKM0(); MFMA_Q(fa1, 1, 1); BAR();
    // P8: slot1 Q(1,0) regs-only
    STG_BU(1, 2, t3); STG_BU(1, 3, t3);
    BAR(); MFMA_Q(fa1, 1, 0); VMW(8); BAR();             // slot0 A-u02+B(t2) landed
  }

  // peeled last iteration (serial reads, same VMW->BAR->read rule)
  {
    const int tL = NT - 1;
    RD_FA(fa0, 0, 0); RD_FB(0, 0);
    STG_AU(1, 1, tL); STG_AU(1, 3, tL);
    BAR(); LGKM0(); MFMA_Q(fa0, 0, 0); BAR();
    RD_FB(0, 1);
    BAR(); LGKM0(); MFMA_Q(fa0, 0, 1); VMW(8); BAR();
    RD_FA(fa1, 0, 1);
    BAR(); LGKM0(); MFMA_Q(fa1, 1, 1); BAR();
    BAR(); MFMA_Q(fa1, 1, 0); VMW(2); BAR();
    RD_FA(fa0, 1, 0); RD_FB(1, 0);
    BAR(); LGKM0(); MFMA_Q(fa0, 0, 0); BAR();
    RD_FB(1, 1);
    BAR(); LGKM0(); MFMA_Q(fa0, 0, 1); VMW(0); BAR();
    RD_FA(fa1, 1, 1);
    BAR(); LGKM0(); MFMA_Q(fa1, 1, 1); BAR();
    BAR(); MFMA_Q(fa1, 1, 0);
  }

#pragma unroll
  for (int mi = 0; mi < 8; mi++)
#pragma unroll
    for (int rr = 0; rr < 4; rr++) {
      int m = m0 + wm * 128 + mi * 16 + quad * 4 + rr;
      u16* crow = C + (size_t)m * N + n0 + wn * 64;
#pragma unroll
      for (int ni = 0; ni < 4; ni++) crow[ni * 16 + lane15] = f2bf(acc[mi][ni][rr]);
    }
}

// ------------------- 128x256 tile (O-projection GEMM) ----------------------
// grid (N/256, M/128) = (14,16) = 224 blocks -> <=1 block/CU, so (512,1).
// r6 schedule (HW-verified): dual fa0/fa1 lookahead, fb keeps BOTH niH sets.
// ---------------------------------------------------------------------------
#define NSTG_A(s, u, t) \
  gl_lds16(pa + (size_t)((u) * 64) * K + (size_t)(t) * 64, \
           ldsw + (s) * 24576 + (u) * 4096)
#define NSTG_B(s, u, t) \
  gl_lds16(pb + (size_t)((u) * 64) * K + (size_t)(t) * 64, \
           ldsw + (s) * 24576 + 8192 + (u) * 4096)

#define NRD_FA(A, s, miH) do { \
  _Pragma("unroll") \
  for (int m2 = 0; m2 < 2; m2++) { \
    const u16* _r = LDS + (s) * 24576 + wm * 4096 + (miH) * 2048 + m2 * 1024 + lane15 * 64; \
    A[m2][0] = *(const short8*)(_r + colA0); \
    A[m2][1] = *(const short8*)(_r + colA1); \
  } \
} while (0)
#define NRD_FB(s, niH) do { \
  _Pragma("unroll") \
  for (int n2 = 0; n2 < 2; n2++) { \
    const u16* _r = LDS + (s) * 24576 + 8192 + wn * 4096 + (niH) * 2048 + n2 * 1024 + lane15 * 64; \
    fb[niH][n2][0] = *(const short8*)(_r + colA0); \
    fb[niH][n2][1] = *(const short8*)(_r + colA1); \
  } \
} while (0)
#define NMFMA_Q(A, miH, niH) do { \
  PRIO1(); \
  _Pragma("unroll") \
  for (int m2 = 0; m2 < 2; m2++) \
    _Pragma("unroll") \
    for (int n2 = 0; n2 < 2; n2++) { \
      acc[(miH) * 2 + m2][(niH) * 2 + n2] = __builtin_amdgcn_mfma_f32_16x16x32_bf16( \
          A[m2][0], fb[niH][n2][0], acc[(miH) * 2 + m2][(niH) * 2 + n2], 0, 0, 0); \
      acc[(miH) * 2 + m2][(niH) * 2 + n2] = __builtin_amdgcn_mfma_f32_16x16x32_bf16( \
          A[m2][1], fb[niH][n2][1], acc[(miH) * 2 + m2][(niH) * 2 + n2], 0, 0, 0); \
    } \
  PRIO0(); \
} while (0)

__global__ __launch_bounds__(512, 1) void gemm8pn_kernel(
    const u16* __restrict__ A, const u16* __restrict__ BT, void* __restrict__ C,
    int M, int N, int K, const int* __restrict__ flagp, int cdyn)
{
  __shared__ __attribute__((aligned(16))) u16 LDS[49152];  // 96 KiB
  const int tid = threadIdx.x;
  const int wave = tid >> 6, lane = tid & 63;
  const int lane15 = lane & 15, quad = lane >> 4;
  const int wm = wave >> 2, wn = wave & 3;
  const int m0 = blockIdx.y * 128, n0 = blockIdx.x * 256;

  const int rloc = wave * 8 + (lane >> 3);
  const int sxor = lane >> 3;
  const int csw = ((lane & 7) ^ sxor) * 8;
  const u16* pa = A + (size_t)(m0 + rloc) * K + csw;
  const u16* pb = BT + (size_t)(n0 + rloc) * K + csw;
  u16* ldsw = LDS + wave * 512;

  const int swz = lane15 & 7;
  const int colA0 = (quad ^ swz) * 8;
  const int colA1 = ((4 + quad) ^ swz) * 8;

  floatx4 acc[4][4];
#pragma unroll
  for (int i = 0; i < 4; i++)
#pragma unroll
    for (int j = 0; j < 4; j++) acc[i][j] = (floatx4){0.f, 0.f, 0.f, 0.f};
  short8 fa0[2][2], fa1[2][2], fb[2][2][2];

  const int NT = K >> 6, NI = NT >> 1;

  // prologue: slot0 <- tile0 (6 loads), slot1 <- tile1 (6 loads)
  NSTG_B(0, 0, 0); NSTG_B(0, 1, 0); NSTG_B(0, 2, 0); NSTG_B(0, 3, 0);
  NSTG_A(0, 0, 0); NSTG_A(0, 1, 0);
  NSTG_B(1, 0, 1); NSTG_B(1, 1, 1); NSTG_B(1, 2, 1); NSTG_B(1, 3, 1);
  NSTG_A(1, 0, 1); NSTG_A(1, 1, 1);
  VMW(6);
  BAR();

  for (int i = 0; i < NI - 1; i++) {
    const int t2 = 2 * i + 2, t3 = 2 * i + 3;
    // P1: slot0 Q(0,0); self (8 reads) + fb1 lookahead (4)
    NRD_FA(fa0, 0, 0); NRD_FB(0, 0);
    SCB();
    NRD_FB(0, 1);
    BAR(); LGKMC(4); NMFMA_Q(fa0, 0, 0); BAR();
    // P2: slot0 Q(0,1); fa1 lookahead (4)
    NRD_FA(fa1, 0, 1);
    BAR(); LGKMC(4); NMFMA_Q(fa0, 0, 1); BAR();
    // P3: slot0 Q(1,1); stage B-s0 <- t2 (B-s0 reads drained P1)
    NSTG_B(0, 0, t2); NSTG_B(0, 1, t2);
    BAR(); LGKM0(); NMFMA_Q(fa1, 1, 1); BAR();
    // P4: slot0 Q(1,0) regs-only; stage rest of slot0 <- t2
    NSTG_B(0, 2, t2); NSTG_B(0, 3, t2); NSTG_A(0, 0, t2); NSTG_A(0, 1, t2);
    BAR(); NMFMA_Q(fa1, 1, 0); VMW(6); BAR();     // slot1 (t1) landed
    // P5: slot1 Q(0,0)
    NRD_FA(fa0, 1, 0); NRD_FB(1, 0);
    SCB();
    NRD_FB(1, 1);
    BAR(); LGKMC(4); NMFMA_Q(fa0, 0, 0); BAR();
    // P6: slot1 Q(0,1)
    NRD_FA(fa1, 1, 1);
    BAR(); LGKMC(4); NMFMA_Q(fa0, 0, 1); BAR();
    // P7: slot1 Q(1,1); stage B-s1 <- t3
    NSTG_B(1, 0, t3); NSTG_B(1, 1, t3);
    BAR(); LGKM0(); NMFMA_Q(fa1, 1, 1); BAR();
    // P8: slot1 Q(1,0) regs-only; stage rest of slot1 <- t3
    NSTG_B(1, 2, t3); NSTG_B(1, 3, t3); NSTG_A(1, 0, t3); NSTG_A(1, 1, t3);
    BAR(); NMFMA_Q(fa1, 1, 0); VMW(6); BAR();     // slot0 (t2) landed
  }

  // peeled last iteration: no staging, serial waits.
  {
    NRD_FA(fa0, 0, 0); NRD_FB(0, 0);
    BAR(); LGKM0(); NMFMA_Q(fa0, 0, 0); BAR();
    NRD_FB(0, 1);
    BAR(); LGKM0(); NMFMA_Q(fa0, 0, 1); BAR();
    NRD_FA(fa1, 0, 1);
    BAR(); LGKM0(); NMFMA_Q(fa1, 1, 1); BAR();
    BAR(); NMFMA_Q(fa1, 1, 0); VMW(0); BAR();     // slot1 (NT-1) landed
    NRD_FA(fa0, 1, 0); NRD_FB(1, 0);
    BAR(); LGKM0(); NMFMA_Q(fa0, 0, 0); BAR();
    NRD_FB(1, 1);
    BAR(); LGKM0(); NMFMA_Q(fa0, 0, 1); BAR();
    NRD_FA(fa1, 1, 1);
    BAR(); LGKM0(); NMFMA_Q(fa1, 1, 1); BAR();
    NMFMA_Q(fa1, 1, 0);
  }

  const bool cf32 = cdyn && (*flagp != 0);
  if (cf32) {
    float* Cf = (float*)C;
#pragma unroll
    for (int mi = 0; mi < 4; mi++)
#pragma unroll
      for (int rr = 0; rr < 4; rr++) {
        int m = m0 + wm * 64 + mi * 16 + quad * 4 + rr;
        float* crow = Cf + (size_t)m * N + n0 + wn * 64;
#pragma unroll
        for (int ni = 0; ni < 4; ni++) crow[ni * 16 + lane15] = acc[mi][ni][rr];
      }
  } else {
    u16* Cb = (u16*)C;
#pragma unroll
    for (int mi = 0; mi < 4; mi++)
#pragma unroll
      for (int rr = 0; rr < 4; rr++) {
        int m = m0 + wm * 64 + mi * 16 + quad * 4 + rr;
        u16* crow = Cb + (size_t)m * N + n0 + wn * 64;
#pragma unroll
        for (int ni = 0; ni < 4; ni++) crow[ni * 16 + lane15] = f2bf(acc[mi][ni][rr]);
      }
  }
}

// ---------------------------------------------------------------------------
// RMS-norm + RoPE, one wave per (s, head).
// ---------------------------------------------------------------------------
__global__ __launch_bounds__(256) void normrope_kernel(
    u16* __restrict__ qkv, const void* __restrict__ qw,
    const void* __restrict__ kw, const void* __restrict__ cosb,
    const void* __restrict__ sinb, const int* __restrict__ flagp)
{
  const bool f32 = (*flagp != 0);
  const int s = blockIdx.x;
  const int wave = threadIdx.x >> 6, lane = threadIdx.x & 63;
  const int hh = blockIdx.y * 4 + wave;
  const int col = (hh < 16) ? hh * 256 : 4096 + (hh - 16) * 256;
  const void* w = (hh < 16) ? qw : kw;
  u16* row = qkv + (size_t)s * 8192 + col;

  float x[4];
#pragma unroll
  for (int j = 0; j < 4; j++) x[j] = bf2f(row[lane + j * 64]);

  float ss = x[0] * x[0] + x[1] * x[1] + x[2] * x[2] + x[3] * x[3];
#pragma unroll
  for (int off = 32; off > 0; off >>= 1) ss += __shfl_xor(ss, off);
  float inv = rsqrtf(ss * (1.0f / 256.0f) + 1e-6f);

  float y[4];
#pragma unroll
  for (int j = 0; j < 4; j++)
    y[j] = x[j] * inv * (1.0f + ldf_dyn(w, lane + j * 64, f32));
  float rot[4] = {-y[2], -y[3], y[0], y[1]};
#pragma unroll
  for (int j = 0; j < 4; j++) {
    int d = lane + j * 64;
    float c = ldf_dyn(cosb, (size_t)s * 256 + d, f32);
    float sn = ldf_dyn(sinb, (size_t)s * 256 + d, f32);
    row[d] = f2bf(y[j] * c + rot[j] * sn);
  }
}

// ---------------------------------------------------------------------------
__global__ __launch_bounds__(256) void vtrans_kernel(
    const u16* __restrict__ qkv, u16* __restrict__ vT)
{
  const int s0 = blockIdx.x * 64, d0 = blockIdx.y * 64, kv = blockIdx.z;
  __shared__ __attribute__((aligned(16))) u16 T[64][72];
  const int tid = threadIdx.x;
#pragma unroll
  for (int i = 0; i < 2; i++) {
    int c = tid + i * 256;
    int r = c >> 3, dc = (c & 7) << 3;
    *(short8*)(&T[r][dc]) =
        *(const short8*)(qkv + (size_t)(s0 + r) * 8192 + 6144 + kv * 256 + d0 + dc);
  }
  __syncthreads();
#pragma unroll
  for (int i = 0; i < 2; i++) {
    int c = tid + i * 256;
    int dr = c >> 3, sc = (c & 7) << 3;
    __attribute__((aligned(16))) u16 tmp[8];
#pragma unroll
    for (int j = 0; j < 8; j++) tmp[j] = T[sc + j][dr];
    *(short8*)(vT + (size_t)kv * 524288 + (size_t)(d0 + dr) * 2048 + s0 + sc) =
        *(const short8*)tmp;
  }
}

// ---------------------------------------------------------------------------
// Flash attention, FIXED-BASE softmax; separate Ks/Vs buffers (r7-verified:
// staged together at tile top, 3 barriers/tile).
// ---------------------------------------------------------------------------
__global__ __launch_bounds__(256) void attn_kernel(
    const u16* __restrict__ qkv, const u16* __restrict__ vT,
    u16* __restrict__ aout)
{
  const int h = blockIdx.y, kvh = h >> 1;
  const int q0 = blockIdx.x * 64;
  const int tid = threadIdx.x;
  const int wave = tid >> 6, lane = tid & 63;
  const int lane15 = lane & 15, quad = lane >> 4;

  __shared__ __attribute__((aligned(16))) u16 Ks[64 * 264];
  __shared__ __attribute__((aligned(16))) u16 Vs[256 * 72];
  __shared__ __attribute__((aligned(16))) u16 Ps[4][16 * 72];

  short8 aq[8];
  const u16* qrow = qkv + (size_t)(q0 + wave * 16 + lane15) * 8192 + h * 256;
#pragma unroll
  for (int kt = 0; kt < 8; kt++)
    aq[kt] = *(const short8*)(qrow + kt * 32 + quad * 8);

  floatx4 zero = {0.0f, 0.0f, 0.0f, 0.0f};
  floatx4 accO[16];
#pragma unroll
  for (int i = 0; i < 16; i++) accO[i] = zero;
  float lR[4] = {0.0f, 0.0f, 0.0f, 0.0f};

  const int iRow = q0 + wave * 16 + quad * 4;
  const int kb_lo = (q0 >= 1023) ? ((q0 - 1023) >> 6) : 0;
  const int kb_hi = q0 >> 6;

  for (int kb = kb_lo; kb <= kb_hi; kb++) {
    const int t0 = kb << 6;
#pragma unroll
    for (int i = 0; i < 8; i++) {
      int c = tid + i * 256;
      int r = c >> 5, dc = (c & 31) << 3;
      *(short8*)(&Ks[r * 264 + dc]) =
          *(const short8*)(qkv + (size_t)(t0 + r) * 8192 + 4096 + kvh * 256 + dc);
    }
#pragma unroll
    for (int i = 0; i < 8; i++) {
      int c = tid + i * 256;
      int dr = c >> 3, tc = (c & 7) << 3;
      *(short8*)(&Vs[dr * 72 + tc]) =
          *(const short8*)(vT + (size_t)kvh * 524288 + (size_t)dr * 2048 + t0 + tc);
    }
    __syncthreads();

    const int relHi = q0 + 16 * wave + 15 - t0;
    const int relLo = q0 + 16 * wave - 1023 - t0;
    const int niHiR = relHi >> 4;
    const int niHi = (niHiR > 3) ? 3 : niHiR;
    int niLo = relLo >> 4; if (niLo < 0) niLo = 0;
    const int ktHiR = relHi >> 5;
    const int ktHi = (ktHiR > 1) ? 1 : ktHiR;
    int ktLo = relLo >> 5; if (ktLo < 0) ktLo = 0;

    float pv[4][4];
#pragma unroll
    for (int ni = 0; ni < 4; ni++) {
      if (ni < niLo || ni > niHi) {
        pv[ni][0] = pv[ni][1] = pv[ni][2] = pv[ni][3] = 0.0f;
        continue;
      }
      floatx4 sAcc = zero;
#pragma unroll
      for (int kt = 0; kt < 8; kt++) {
        short8 bk = *(const short8*)(&Ks[(ni * 16 + lane15) * 264 + kt * 32 + quad * 8]);
        sAcc = __builtin_amdgcn_mfma_f32_16x16x32_bf16(aq[kt], bk, sAcc, 0, 0, 0);
      }
#pragma unroll
      for (int r = 0; r < 4; r++) {
        float x = sAcc[r] * 0.00125f;
        float ax = __builtin_fabsf(x);
        float e2 = __expf(ax + ax);
        float t = 1.0f - 2.0f * __builtin_amdgcn_rcpf(e2 + 1.0f);
        float sv = copysignf(t, x) * 50.0f;
        int i_ = iRow + r;
        int j_ = t0 + ni * 16 + lane15;
        bool ok = (j_ <= i_) && (i_ - j_ < 1024);
        pv[ni][r] = ok ? __expf(sv) : 0.0f;
      }
    }
#pragma unroll
    for (int r = 0; r < 4; r++)
      lR[r] += pv[0][r] + pv[1][r] + pv[2][r] + pv[3][r];

#pragma unroll
    for (int ni = 0; ni < 4; ni++)
#pragma unroll
      for (int r = 0; r < 4; r++)
        Ps[wave][(quad * 4 + r) * 72 + ni * 16 + lane15] = f2bf(pv[ni][r]);
    __syncthreads();

#pragma unroll
    for (int ktile = 0; ktile < 2; ktile++) {
      if (ktile < ktLo || ktile > ktHi) continue;
      short8 ap = *(const short8*)(&Ps[wave][lane15 * 72 + ktile * 32 + quad * 8]);
#pragma unroll
      for (int ni = 0; ni < 16; ni++) {
        short8 bv = *(const short8*)(&Vs[(ni * 16 + lane15) * 72 + ktile * 32 + quad * 8]);
        accO[ni] = __builtin_amdgcn_mfma_f32_16x16x32_bf16(ap, bv, accO[ni], 0, 0, 0);
      }
    }
    __syncthreads();
  }

#pragma unroll
  for (int r = 0; r < 4; r++) {
    float l = lR[r];
    l += __shfl_xor(l, 1);
    l += __shfl_xor(l, 2);
    l += __shfl_xor(l, 4);
    l += __shfl_xor(l, 8);
    float invl = 1.0f / l;
    u16* orow = aout + (size_t)(q0 + wave * 16 + quad * 4 + r) * 4096 + h * 256;
#pragma unroll
    for (int ni = 0; ni < 16; ni++)
      orow[ni * 16 + lane15] = f2bf(accO[ni][r] * invl);
  }
}

// ---------------------------------------------------------------------------
extern "C" void kernel_launch(void* const* d_in, const int* in_sizes, int n_in,
                              void* d_out, int out_size, void* d_ws, size_t ws_size,
                              hipStream_t stream)
{
  const void* hidden = d_in[0];
  const void* w_qkv  = d_in[1];
  const void* w_o    = d_in[2];
  const void* q_w    = d_in[3];
  const void* k_w    = d_in[4];
  const void* cosb   = d_in[5];
  const void* sinb   = d_in[6];

  char* ws = (char*)d_ws;
  int* flag = (int*)ws;                                   ws += 256;
  u16* qkv  = (u16*)ws;  ws += (size_t)2048 * 8192 * 2;
  u16* vT   = (u16*)ws;  ws += (size_t)8 * 256 * 2048 * 2;
  u16* aout = (u16*)ws;  ws += (size_t)2048 * 4096 * 2;
  u16* hb   = (u16*)ws;  ws += (size_t)2048 * 3584 * 2;
  u16* wT   = (u16*)ws;

  probe_dtype_kernel<<<1, 256, 0, stream>>>(hidden, flag);
  convert_dyn_kernel<<<3584, 256, 0, stream>>>(hidden, hb, (size_t)2048 * 3584, flag);
  transpose_dyn_kernel<<<dim3(128, 56), 256, 0, stream>>>(w_qkv, wT, 3584, 8192, flag);
  gemm8p_kernel<<<dim3(32, 8), 512, 0, stream>>>(hidden, hb, wT, qkv, 2048, 8192, 3584, flag);
  normrope_kernel<<<dim3(2048, 6), 256, 0, stream>>>(qkv, q_w, k_w, cosb, sinb, flag);
  transpose_dyn_kernel<<<dim3(56, 64), 256, 0, stream>>>(w_o, wT, 4096, 3584, flag);
  vtrans_kernel<<<dim3(32, 4, 8), 256, 0, stream>>>(qkv, vT);
  attn_kernel<<<dim3(32, 16), 256, 0, stream>>>(qkv, vT, aout);
  gemm8pn_kernel<<<dim3(14, 16), 512, 0, stream>>>(aout, wT, d_out, 2048, 3584, 4096, flag, 1);
}

// Round 11
// 515.609 us; speedup vs baseline: 1.2560x; 1.2560x over previous
//
#include <hip/hip_runtime.h>
#include <hip/hip_bf16.h>
#include <math.h>

typedef __attribute__((ext_vector_type(8))) short short8;
typedef __attribute__((ext_vector_type(4))) float floatx4;
typedef unsigned short u16;

typedef __attribute__((address_space(1))) const void* gas_ptr;
typedef __attribute__((address_space(3))) void* las_ptr;

__device__ __forceinline__ float bf2f(u16 h) {
  union { unsigned u; float f; } v; v.u = ((unsigned)h) << 16; return v.f;
}
__device__ __forceinline__ u16 f2bf(float f) {
  union { float f; unsigned u; } v; v.f = f;
  unsigned r = v.u + 0x7FFFu + ((v.u >> 16) & 1u);
  return (u16)(r >> 16);
}
__device__ __forceinline__ float ldf_dyn(const void* p, size_t i, bool f32) {
  return f32 ? ((const float*)p)[i] : bf2f(((const u16*)p)[i]);
}
__device__ __forceinline__ short8 load8_dyn(const void* p, size_t idx, bool f32) {
  if (f32) {
    const float* f = (const float*)p;
    float4 a = *(const float4*)(f + idx);
    float4 b = *(const float4*)(f + idx + 4);
    short8 r;
    r[0] = (short)f2bf(a.x); r[1] = (short)f2bf(a.y);
    r[2] = (short)f2bf(a.z); r[3] = (short)f2bf(a.w);
    r[4] = (short)f2bf(b.x); r[5] = (short)f2bf(b.y);
    r[6] = (short)f2bf(b.z); r[7] = (short)f2bf(b.w);
    return r;
  }
  return *(const short8*)((const u16*)p + idx);
}
__device__ __forceinline__ void gl_lds16(const u16* g, u16* l) {
  __builtin_amdgcn_global_load_lds((gas_ptr)g, (las_ptr)l, 16, 0, 0);
}

// ---------------------------------------------------------------------------
__global__ void probe_dtype_kernel(const void* hidden, int* flag) {
  __shared__ int cnt;
  if (threadIdx.x == 0) cnt = 0;
  __syncthreads();
  const u16* h = (const u16*)hidden;
  int local = 0;
  for (int i = threadIdx.x; i < 8192; i += 256) {
    u16 u = h[i];
    int e = (u >> 7) & 0xFF;
    if ((e >= 64 && e <= 160) || (u & 0x7FFF) == 0) local++;
  }
  atomicAdd(&cnt, local);
  __syncthreads();
  if (threadIdx.x == 0) *flag = (cnt < 7700) ? 1 : 0;
}

// ---------------------------------------------------------------------------
// Only copies when input is f32 (bf16 input is consumed in place by gemm8p).
__global__ __launch_bounds__(256) void convert_dyn_kernel(
    const void* __restrict__ src, u16* __restrict__ dst, size_t n,
    const int* __restrict__ flagp)
{
  if (*flagp == 0) return;  // bf16: gemm8p reads src directly
  size_t i = ((size_t)blockIdx.x * 256 + threadIdx.x) * 8;
  if (i < n) *(short8*)(dst + i) = load8_dyn(src, i, true);
}

// ---------------------------------------------------------------------------
__global__ __launch_bounds__(256) void transpose_dyn_kernel(
    const void* __restrict__ src, u16* __restrict__ dst, int R, int C,
    const int* __restrict__ flagp)
{
  const bool f32 = (*flagp != 0);
  const int c0 = blockIdx.x * 64, r0 = blockIdx.y * 64;
  __shared__ __attribute__((aligned(16))) u16 T[64][72];
  const int tid = threadIdx.x;
#pragma unroll
  for (int i = 0; i < 2; i++) {
    int t = tid + i * 256;
    int r = t >> 3, cc = (t & 7) << 3;
    *(short8*)(&T[r][cc]) = load8_dyn(src, (size_t)(r0 + r) * C + c0 + cc, f32);
  }
  __syncthreads();
#pragma unroll
  for (int i = 0; i < 2; i++) {
    int t = tid + i * 256;
    int cr = t >> 3, rc = (t & 7) << 3;
    __attribute__((aligned(16))) u16 tmp[8];
#pragma unroll
    for (int j = 0; j < 8; j++) tmp[j] = T[rc + j][cr];
    *(short8*)(dst + (size_t)(c0 + cr) * R + r0 + rc) = *(const short8*)tmp;
  }
}

// ---------------------------------------------------------------------------
// Shared scheduling primitives for the 8-phase GEMMs.
// Swizzle f(r) = r&7: conflict-free ds_read_b128 (r5: 0 conflicts).
// SAFETY INVARIANTS:
//  - vmcnt is PER-WAVE; every VMW(n) gating a staged region is followed by
//    BAR() BEFORE any ds_read of that region; regions re-staged only strictly
//    after their last-read phase.
//  - REGISTER WALL (r6+r10, twice-measured): 512-thread block => 2 waves/SIMD
//    => 256 UNIFIED (VGPR+AGPR) regs/wave cap, launch_bounds cannot raise it.
//    acc(128 AGPR)+fa(32)+fb(32)+addressing is full. No extra fragment sets.
//  - Counted-lgkm ladder rule (r8): an MFMA group may only consume fragments
//    whose reads are COVERED BY THE COUNT.
// ---------------------------------------------------------------------------
#define BAR() __builtin_amdgcn_s_barrier()
#define SCB() __builtin_amdgcn_sched_barrier(0)
#define LGKM0() do { asm volatile("s_waitcnt lgkmcnt(0)" ::: "memory"); SCB(); } while (0)
#define LGKMC(n) do { asm volatile("s_waitcnt lgkmcnt(" #n ")" ::: "memory"); SCB(); } while (0)
#define VMW(n) do { asm volatile("s_waitcnt vmcnt(" #n ")" ::: "memory"); SCB(); } while (0)
#define PRIO1() __builtin_amdgcn_s_setprio(1)
#define PRIO0() do { __builtin_amdgcn_s_setprio(0); SCB(); } while (0)

// ------------------------- 256x256 tile (QKV GEMM) -------------------------
#define STG_AU(s, u, t) \
  gl_lds16(pa + (size_t)((u) * 64) * K + (size_t)(t) * 64, \
           ldsw + (s) * 32768 + (u) * 4096)
#define STG_BU(s, u, t) \
  gl_lds16(pb + (size_t)((u) * 64) * K + (size_t)(t) * 64, \
           ldsw + (s) * 32768 + 16384 + (u) * 4096)

#define RD_FA(s, miH) do { \
  _Pragma("unroll") \
  for (int m2 = 0; m2 < 4; m2++) { \
    const u16* _r = LDS + (s) * 32768 + wm * 8192 + (miH) * 4096 + m2 * 1024 + lane15 * 64; \
    fa[m2][0] = *(const short8*)(_r + colA0); \
    fa[m2][1] = *(const short8*)(_r + colA1); \
  } \
} while (0)
#define RD_FB(s, niH) do { \
  _Pragma("unroll") \
  for (int n2 = 0; n2 < 2; n2++) { \
    const u16* _r = LDS + (s) * 32768 + 16384 + wn * 4096 + (niH) * 2048 + n2 * 1024 + lane15 * 64; \
    fb[niH][n2][0] = *(const short8*)(_r + colA0); \
    fb[niH][n2][1] = *(const short8*)(_r + colA1); \
  } \
} while (0)
#define RD_FA1(s, miH, m2v) do { \
  const u16* _r = LDS + (s) * 32768 + wm * 8192 + (miH) * 4096 + (m2v) * 1024 + lane15 * 64; \
  fa[m2v][0] = *(const short8*)(_r + colA0); \
  fa[m2v][1] = *(const short8*)(_r + colA1); \
} while (0)
#define RD_FB1(s, niH, n2v) do { \
  const u16* _r = LDS + (s) * 32768 + 16384 + wn * 4096 + (niH) * 2048 + (n2v) * 1024 + lane15 * 64; \
  fb[niH][n2v][0] = *(const short8*)(_r + colA0); \
  fb[niH][n2v][1] = *(const short8*)(_r + colA1); \
} while (0)

#define MFMA_M2(m2v, miH, niH) do { \
  _Pragma("unroll") \
  for (int n2 = 0; n2 < 2; n2++) { \
    acc[(miH) * 4 + (m2v)][(niH) * 2 + n2] = __builtin_amdgcn_mfma_f32_16x16x32_bf16( \
        fa[m2v][0], fb[niH][n2][0], acc[(miH) * 4 + (m2v)][(niH) * 2 + n2], 0, 0, 0); \
    acc[(miH) * 4 + (m2v)][(niH) * 2 + n2] = __builtin_amdgcn_mfma_f32_16x16x32_bf16( \
        fa[m2v][1], fb[niH][n2][1], acc[(miH) * 4 + (m2v)][(niH) * 2 + n2], 0, 0, 0); \
  } \
} while (0)
#define MFMA_N2(n2v, miH, niH) do { \
  _Pragma("unroll") \
  for (int m2 = 0; m2 < 4; m2++) { \
    acc[(miH) * 4 + m2][(niH) * 2 + (n2v)] = __builtin_amdgcn_mfma_f32_16x16x32_bf16( \
        fa[m2][0], fb[niH][n2v][0], acc[(miH) * 4 + m2][(niH) * 2 + (n2v)], 0, 0, 0); \
    acc[(miH) * 4 + m2][(niH) * 2 + (n2v)] = __builtin_amdgcn_mfma_f32_16x16x32_bf16( \
        fa[m2][1], fb[niH][n2v][1], acc[(miH) * 4 + m2][(niH) * 2 + (n2v)], 0, 0, 0); \
  } \
} while (0)
#define MFMA_Q(miH, niH) do { \
  PRIO1(); \
  _Pragma("unroll") \
  for (int m2 = 0; m2 < 4; m2++) \
    _Pragma("unroll") \
    for (int n2 = 0; n2 < 2; n2++) { \
      acc[(miH) * 4 + m2][(niH) * 2 + n2] = __builtin_amdgcn_mfma_f32_16x16x32_bf16( \
          fa[m2][0], fb[niH][n2][0], acc[(miH) * 4 + m2][(niH) * 2 + n2], 0, 0, 0); \
      acc[(miH) * 4 + m2][(niH) * 2 + n2] = __builtin_amdgcn_mfma_f32_16x16x32_bf16( \
          fa[m2][1], fb[niH][n2][1], acc[(miH) * 4 + m2][(niH) * 2 + n2], 0, 0, 0); \
    } \
  PRIO0(); \
} while (0)

__global__ __launch_bounds__(512, 2) void gemm8p_kernel(
    const void* __restrict__ Araw, const u16* __restrict__ Ahb,
    const u16* __restrict__ BT, u16* __restrict__ C,
    int M, int N, int K, const int* __restrict__ flagp)
{
  __shared__ __attribute__((aligned(16))) u16 LDS[65536];  // 128 KiB
  const int tid = threadIdx.x;
  const int wave = tid >> 6, lane = tid & 63;
  const int lane15 = lane & 15, quad = lane >> 4;
  const int wm = wave >> 2, wn = wave & 3;
  const int m0 = blockIdx.y * 256, n0 = blockIdx.x * 256;

  const u16* Abase = (*flagp != 0) ? Ahb : (const u16*)Araw;

  const int rloc = wave * 8 + (lane >> 3);
  const int sxor = lane >> 3;
  const int csw = ((lane & 7) ^ sxor) * 8;  // u16 units
  const u16* pa = Abase + (size_t)(m0 + rloc) * K + csw;
  const u16* pb = BT + (size_t)(n0 + rloc) * K + csw;
  u16* ldsw = LDS + wave * 512;

  const int swz = lane15 & 7;
  const int colA0 = (quad ^ swz) * 8;
  const int colA1 = ((4 + quad) ^ swz) * 8;

  floatx4 acc[8][4];
#pragma unroll
  for (int i = 0; i < 8; i++)
#pragma unroll
    for (int j = 0; j < 4; j++) acc[i][j] = (floatx4){0.f, 0.f, 0.f, 0.f};
  short8 fa[4][2], fb[2][2][2];

  const int NT = K >> 6, NI = NT >> 1;

  STG_AU(0, 0, 0); STG_AU(0, 2, 0);
  STG_BU(0, 0, 0); STG_BU(0, 1, 0);
  STG_BU(0, 2, 0); STG_BU(0, 3, 0);
  STG_AU(0, 1, 0); STG_AU(0, 3, 0);
  STG_AU(1, 0, 1); STG_AU(1, 2, 1);
  STG_BU(1, 0, 1); STG_BU(1, 1, 1);
  STG_BU(1, 2, 1); STG_BU(1, 3, 1);
  VMW(8);
  BAR();

  for (int i = 0; i < NI - 1; i++) {
    const int t1 = 2 * i + 1, t2 = 2 * i + 2, t3 = 2 * i + 3;
    // P1: reads fb0(4) then fa0..3(2 each); ladder overlaps fa-tail with MFMA
    RD_FB(0, 0); SCB();
    RD_FA1(0, 0, 0); SCB(); RD_FA1(0, 0, 1); SCB();
    RD_FA1(0, 0, 2); SCB(); RD_FA1(0, 0, 3); SCB();
    STG_AU(1, 1, t1); STG_AU(1, 3, t1);
    BAR(); PRIO1();
    LGKMC(6); MFMA_M2(0, 0, 0);
    LGKMC(4); MFMA_M2(1, 0, 0);
    LGKMC(2); MFMA_M2(2, 0, 0);
    LGKM0();  MFMA_M2(3, 0, 0);
    PRIO0(); BAR();
    // P2: reads fb1 (2+2)
    RD_FB1(0, 1, 0); SCB(); RD_FB1(0, 1, 1); SCB();
    STG_AU(0, 0, t2); STG_AU(0, 2, t2);
    BAR(); PRIO1();
    LGKMC(2); MFMA_N2(0, 0, 1);
    LGKM0();  MFMA_N2(1, 0, 1);
    PRIO0(); VMW(10); BAR();                 // A-s0-u13(t) landed
    // P3: reads fa(miH=1) (2x4)
    RD_FA1(0, 1, 0); SCB(); RD_FA1(0, 1, 1); SCB();
    RD_FA1(0, 1, 2); SCB(); RD_FA1(0, 1, 3); SCB();
    STG_BU(0, 0, t2); STG_BU(0, 1, t2);
    BAR(); PRIO1();
    LGKMC(6); MFMA_M2(0, 1, 1);
    LGKMC(4); MFMA_M2(1, 1, 1);
    LGKMC(2); MFMA_M2(2, 1, 1);
    LGKM0();  MFMA_M2(3, 1, 1);
    PRIO0(); BAR();
    // P4: regs-only
    STG_BU(0, 2, t2); STG_BU(0, 3, t2);
    BAR(); MFMA_Q(1, 0); VMW(8); BAR();      // slot1 A-u02+B(t1) landed
    // P5
    RD_FB(1, 0); SCB();
    RD_FA1(1, 0, 0); SCB(); RD_FA1(1, 0, 1); SCB();
    RD_FA1(1, 0, 2); SCB(); RD_FA1(1, 0, 3); SCB();
    STG_AU(0, 1, t2); STG_AU(0, 3, t2);
    BAR(); PRIO1();
    LGKMC(6); MFMA_M2(0, 0, 0);
    LGKMC(4); MFMA_M2(1, 0, 0);
    LGKMC(2); MFMA_M2(2, 0, 0);
    LGKM0();  MFMA_M2(3, 0, 0);
    PRIO0(); BAR();
    // P6
    RD_FB1(1, 1, 0); SCB(); RD_FB1(1, 1, 1); SCB();
    STG_AU(1, 0, t3); STG_AU(1, 2, t3);
    BAR(); PRIO1();
    LGKMC(2); MFMA_N2(0, 0, 1);
    LGKM0();  MFMA_N2(1, 0, 1);
    PRIO0(); VMW(10); BAR();                 // A-s1-u13(t1) landed
    // P7
    RD_FA1(1, 1, 0); SCB(); RD_FA1(1, 1, 1); SCB();
    RD_FA1(1, 1, 2); SCB(); RD_FA1(1, 1, 3); SCB();
    STG_BU(1, 0, t3); STG_BU(1, 1, t3);
    BAR(); PRIO1();
    LGKMC(6); MFMA_M2(0, 1, 1);
    LGKMC(4); MFMA_M2(1, 1, 1);
    LGKMC(2); MFMA_M2(2, 1, 1);
    LGKM0();  MFMA_M2(3, 1, 1);
    PRIO0(); BAR();
    // P8: regs-only
    STG_BU(1, 2, t3); STG_BU(1, 3, t3);
    BAR(); MFMA_Q(1, 0); VMW(8); BAR();      // slot0 A-u02+B(t2) landed
  }

  // peeled last iteration (serial reads; same VMW->BAR->read rule)
  {
    const int tL = NT - 1;
    RD_FA(0, 0); RD_FB(0, 0);
    STG_AU(1, 1, tL); STG_AU(1, 3, tL);
    BAR(); LGKM0(); MFMA_Q(0, 0); BAR();
    RD_FB(0, 1);
    BAR(); LGKM0(); MFMA_Q(0, 1); VMW(8); BAR();
    RD_FA(0, 1);
    BAR(); LGKM0(); MFMA_Q(1, 1); BAR();
    BAR(); MFMA_Q(1, 0); VMW(2); BAR();
    RD_FA(1, 0); RD_FB(1, 0);
    BAR(); LGKM0(); MFMA_Q(0, 0); BAR();
    RD_FB(1, 1);
    BAR(); LGKM0(); MFMA_Q(0, 1); VMW(0); BAR();
    RD_FA(1, 1);
    BAR(); LGKM0(); MFMA_Q(1, 1); BAR();
    BAR(); MFMA_Q(1, 0);
  }

#pragma unroll
  for (int mi = 0; mi < 8; mi++)
#pragma unroll
    for (int rr = 0; rr < 4; rr++) {
      int m = m0 + wm * 128 + mi * 16 + quad * 4 + rr;
      u16* crow = C + (size_t)m * N + n0 + wn * 64;
#pragma unroll
      for (int ni = 0; ni < 4; ni++) crow[ni * 16 + lane15] = f2bf(acc[mi][ni][rr]);
    }
}

// ------------------- 128x256 tile (O-projection GEMM) ----------------------
// Round-7/9-verified serial-wait version; fb keeps both niH sets.
// ---------------------------------------------------------------------------
#define NSTG_A(s, u, t) \
  gl_lds16(pa + (size_t)((u) * 64) * K + (size_t)(t) * 64, \
           ldsw + (s) * 24576 + (u) * 4096)
#define NSTG_B(s, u, t) \
  gl_lds16(pb + (size_t)((u) * 64) * K + (size_t)(t) * 64, \
           ldsw + (s) * 24576 + 8192 + (u) * 4096)

#define NRD_FA(s, miH) do { \
  _Pragma("unroll") \
  for (int m2 = 0; m2 < 2; m2++) { \
    const u16* _r = LDS + (s) * 24576 + wm * 4096 + (miH) * 2048 + m2 * 1024 + lane15 * 64; \
    fa[m2][0] = *(const short8*)(_r + colA0); \
    fa[m2][1] = *(const short8*)(_r + colA1); \
  } \
} while (0)
#define NRD_FB(s, niH) do { \
  _Pragma("unroll") \
  for (int n2 = 0; n2 < 2; n2++) { \
    const u16* _r = LDS + (s) * 24576 + 8192 + wn * 4096 + (niH) * 2048 + n2 * 1024 + lane15 * 64; \
    fb[niH][n2][0] = *(const short8*)(_r + colA0); \
    fb[niH][n2][1] = *(const short8*)(_r + colA1); \
  } \
} while (0)
#define NMFMA_Q(miH, niH) do { \
  PRIO1(); \
  _Pragma("unroll") \
  for (int m2 = 0; m2 < 2; m2++) \
    _Pragma("unroll") \
    for (int n2 = 0; n2 < 2; n2++) { \
      acc[(miH) * 2 + m2][(niH) * 2 + n2] = __builtin_amdgcn_mfma_f32_16x16x32_bf16( \
          fa[m2][0], fb[niH][n2][0], acc[(miH) * 2 + m2][(niH) * 2 + n2], 0, 0, 0); \
      acc[(miH) * 2 + m2][(niH) * 2 + n2] = __builtin_amdgcn_mfma_f32_16x16x32_bf16( \
          fa[m2][1], fb[niH][n2][1], acc[(miH) * 2 + m2][(niH) * 2 + n2], 0, 0, 0); \
    } \
  PRIO0(); \
} while (0)

__global__ __launch_bounds__(512, 2) void gemm8pn_kernel(
    const u16* __restrict__ A, const u16* __restrict__ BT, void* __restrict__ C,
    int M, int N, int K, const int* __restrict__ flagp, int cdyn)
{
  __shared__ __attribute__((aligned(16))) u16 LDS[49152];  // 96 KiB
  const int tid = threadIdx.x;
  const int wave = tid >> 6, lane = tid & 63;
  const int lane15 = lane & 15, quad = lane >> 4;
  const int wm = wave >> 2, wn = wave & 3;
  const int m0 = blockIdx.y * 128, n0 = blockIdx.x * 256;

  const int rloc = wave * 8 + (lane >> 3);
  const int sxor = lane >> 3;
  const int csw = ((lane & 7) ^ sxor) * 8;
  const u16* pa = A + (size_t)(m0 + rloc) * K + csw;
  const u16* pb = BT + (size_t)(n0 + rloc) * K + csw;
  u16* ldsw = LDS + wave * 512;

  const int swz = lane15 & 7;
  const int colA0 = (quad ^ swz) * 8;
  const int colA1 = ((4 + quad) ^ swz) * 8;

  floatx4 acc[4][4];
#pragma unroll
  for (int i = 0; i < 4; i++)
#pragma unroll
    for (int j = 0; j < 4; j++) acc[i][j] = (floatx4){0.f, 0.f, 0.f, 0.f};
  short8 fa[2][2], fb[2][2][2];

  const int NT = K >> 6, NI = NT >> 1;

  NSTG_B(0, 0, 0); NSTG_B(0, 1, 0); NSTG_B(0, 2, 0); NSTG_B(0, 3, 0);
  NSTG_A(0, 0, 0); NSTG_A(0, 1, 0);
  NSTG_B(1, 0, 1); NSTG_B(1, 1, 1); NSTG_B(1, 2, 1); NSTG_B(1, 3, 1);
  NSTG_A(1, 0, 1); NSTG_A(1, 1, 1);
  VMW(6);
  BAR();

  for (int i = 0; i < NI - 1; i++) {
    const int t2 = 2 * i + 2, t3 = 2 * i + 3;
    // P1
    NRD_FA(0, 0); NRD_FB(0, 0);
    BAR(); LGKM0(); NMFMA_Q(0, 0); BAR();
    // P2
    NRD_FB(0, 1);
    BAR(); LGKM0(); NMFMA_Q(0, 1); BAR();
    // P3
    NRD_FA(0, 1);
    NSTG_B(0, 0, t2); NSTG_B(0, 1, t2);
    BAR(); LGKM0(); NMFMA_Q(1, 1); BAR();
    // P4
    NSTG_B(0, 2, t2); NSTG_B(0, 3, t2); NSTG_A(0, 0, t2); NSTG_A(0, 1, t2);
    BAR(); NMFMA_Q(1, 0); VMW(6); BAR();
    // P5
    NRD_FA(1, 0); NRD_FB(1, 0);
    BAR(); LGKM0(); NMFMA_Q(0, 0); BAR();
    // P6
    NRD_FB(1, 1);
    BAR(); LGKM0(); NMFMA_Q(0, 1); BAR();
    // P7
    NRD_FA(1, 1);
    NSTG_B(1, 0, t3); NSTG_B(1, 1, t3);
    BAR(); LGKM0(); NMFMA_Q(1, 1); BAR();
    // P8
    NSTG_B(1, 2, t3); NSTG_B(1, 3, t3); NSTG_A(1, 0, t3); NSTG_A(1, 1, t3);
    BAR(); NMFMA_Q(1, 0); VMW(6); BAR();
  }

  {
    NRD_FA(0, 0); NRD_FB(0, 0);
    BAR(); LGKM0(); NMFMA_Q(0, 0); BAR();
    NRD_FB(0, 1);
    BAR(); LGKM0(); NMFMA_Q(0, 1); BAR();
    NRD_FA(0, 1);
    BAR(); LGKM0(); NMFMA_Q(1, 1); BAR();
    BAR(); NMFMA_Q(1, 0); VMW(0); BAR();
    NRD_FA(1, 0); NRD_FB(1, 0);
    BAR(); LGKM0(); NMFMA_Q(0, 0); BAR();
    NRD_FB(1, 1);
    BAR(); LGKM0(); NMFMA_Q(0, 1); BAR();
    NRD_FA(1, 1);
    BAR(); LGKM0(); NMFMA_Q(1, 1); BAR();
    NMFMA_Q(1, 0);
  }

  const bool cf32 = cdyn && (*flagp != 0);
  if (cf32) {
    float* Cf = (float*)C;
#pragma unroll
    for (int mi = 0; mi < 4; mi++)
#pragma unroll
      for (int rr = 0; rr < 4; rr++) {
        int m = m0 + wm * 64 + mi * 16 + quad * 4 + rr;
        float* crow = Cf + (size_t)m * N + n0 + wn * 64;
#pragma unroll
        for (int ni = 0; ni < 4; ni++) crow[ni * 16 + lane15] = acc[mi][ni][rr];
      }
  } else {
    u16* Cb = (u16*)C;
#pragma unroll
    for (int mi = 0; mi < 4; mi++)
#pragma unroll
      for (int rr = 0; rr < 4; rr++) {
        int m = m0 + wm * 64 + mi * 16 + quad * 4 + rr;
        u16* crow = Cb + (size_t)m * N + n0 + wn * 64;
#pragma unroll
        for (int ni = 0; ni < 4; ni++) crow[ni * 16 + lane15] = f2bf(acc[mi][ni][rr]);
      }
  }
}

// ---------------------------------------------------------------------------
// RMS-norm + RoPE, one wave per (s, head).
// ---------------------------------------------------------------------------
__global__ __launch_bounds__(256) void normrope_kernel(
    u16* __restrict__ qkv, const void* __restrict__ qw,
    const void* __restrict__ kw, const void* __restrict__ cosb,
    const void* __restrict__ sinb, const int* __restrict__ flagp)
{
  const bool f32 = (*flagp != 0);
  const int s = blockIdx.x;
  const int wave = threadIdx.x >> 6, lane = threadIdx.x & 63;
  const int hh = blockIdx.y * 4 + wave;
  const int col = (hh < 16) ? hh * 256 : 4096 + (hh - 16) * 256;
  const void* w = (hh < 16) ? qw : kw;
  u16* row = qkv + (size_t)s * 8192 + col;

  float x[4];
#pragma unroll
  for (int j = 0; j < 4; j++) x[j] = bf2f(row[lane + j * 64]);

  float ss = x[0] * x[0] + x[1] * x[1] + x[2] * x[2] + x[3] * x[3];
#pragma unroll
  for (int off = 32; off > 0; off >>= 1) ss += __shfl_xor(ss, off);
  float inv = rsqrtf(ss * (1.0f / 256.0f) + 1e-6f);

  float y[4];
#pragma unroll
  for (int j = 0; j < 4; j++)
    y[j] = x[j] * inv * (1.0f + ldf_dyn(w, lane + j * 64, f32));
  float rot[4] = {-y[2], -y[3], y[0], y[1]};
#pragma unroll
  for (int j = 0; j < 4; j++) {
    int d = lane + j * 64;
    float c = ldf_dyn(cosb, (size_t)s * 256 + d, f32);
    float sn = ldf_dyn(sinb, (size_t)s * 256 + d, f32);
    row[d] = f2bf(y[j] * c + rot[j] * sn);
  }
}

// ---------------------------------------------------------------------------
__global__ __launch_bounds__(256) void vtrans_kernel(
    const u16* __restrict__ qkv, u16* __restrict__ vT)
{
  const int s0 = blockIdx.x * 64, d0 = blockIdx.y * 64, kv = blockIdx.z;
  __shared__ __attribute__((aligned(16))) u16 T[64][72];
  const int tid = threadIdx.x;
#pragma unroll
  for (int i = 0; i < 2; i++) {
    int c = tid + i * 256;
    int r = c >> 3, dc = (c & 7) << 3;
    *(short8*)(&T[r][dc]) =
        *(const short8*)(qkv + (size_t)(s0 + r) * 8192 + 6144 + kv * 256 + d0 + dc);
  }
  __syncthreads();
#pragma unroll
  for (int i = 0; i < 2; i++) {
    int c = tid + i * 256;
    int dr = c >> 3, sc = (c & 7) << 3;
    __attribute__((aligned(16))) u16 tmp[8];
#pragma unroll
    for (int j = 0; j < 8; j++) tmp[j] = T[sc + j][dr];
    *(short8*)(vT + (size_t)kv * 524288 + (size_t)(d0 + dr) * 2048 + s0 + sc) =
        *(const short8*)tmp;
  }
}

// ---------------------------------------------------------------------------
// Flash attention, FIXED-BASE softmax; separate Ks/Vs buffers staged together
// at tile top (r7). r11: QBLK=128, 512 threads (8 waves x 16 q-rows), grid
// (16,16)=256 blocks -> 1 block/CU, same 8 waves/CU as before but HALF the
// K/V staging bytes and barriers per MFMA. Per-wave mask bounds (relHi/relLo)
// unchanged; waves with no in-range tiles skip compute but co-stage.
// LDS = 33+36+18 = 87 KB.
// ---------------------------------------------------------------------------
__global__ __launch_bounds__(512) void attn_kernel(
    const u16* __restrict__ qkv, const u16* __restrict__ vT,
    u16* __restrict__ aout)
{
  const int h = blockIdx.y, kvh = h >> 1;
  const int q0 = blockIdx.x * 128;
  const int tid = threadIdx.x;
  const int wave = tid >> 6, lane = tid & 63;
  const int lane15 = lane & 15, quad = lane >> 4;

  __shared__ __attribute__((aligned(16))) u16 Ks[64 * 264];
  __shared__ __attribute__((aligned(16))) u16 Vs[256 * 72];
  __shared__ __attribute__((aligned(16))) u16 Ps[8][16 * 72];

  short8 aq[8];
  const u16* qrow = qkv + (size_t)(q0 + wave * 16 + lane15) * 8192 + h * 256;
#pragma unroll
  for (int kt = 0; kt < 8; kt++)
    aq[kt] = *(const short8*)(qrow + kt * 32 + quad * 8);

  floatx4 zero = {0.0f, 0.0f, 0.0f, 0.0f};
  floatx4 accO[16];
#pragma unroll
  for (int i = 0; i < 16; i++) accO[i] = zero;
  float lR[4] = {0.0f, 0.0f, 0.0f, 0.0f};

  const int iRow = q0 + wave * 16 + quad * 4;
  const int kb_lo = (q0 >= 1023) ? ((q0 - 1023) >> 6) : 0;
  const int kb_hi = (q0 + 127) >> 6;

  for (int kb = kb_lo; kb <= kb_hi; kb++) {
    const int t0 = kb << 6;
    // stage K (64x256) and V^T (256x64) together -- latencies overlap
#pragma unroll
    for (int i = 0; i < 4; i++) {
      int c = tid + i * 512;
      int r = c >> 5, dc = (c & 31) << 3;
      *(short8*)(&Ks[r * 264 + dc]) =
          *(const short8*)(qkv + (size_t)(t0 + r) * 8192 + 4096 + kvh * 256 + dc);
    }
#pragma unroll
    for (int i = 0; i < 4; i++) {
      int c = tid + i * 512;
      int dr = c >> 3, tc = (c & 7) << 3;
      *(short8*)(&Vs[dr * 72 + tc]) =
          *(const short8*)(vT + (size_t)kvh * 524288 + (size_t)dr * 2048 + t0 + tc);
    }
    __syncthreads();

    // wave-uniform skip bounds (group fully above diagonal / below window)
    const int relHi = q0 + 16 * wave + 15 - t0;          // may be negative now
    const int relLo = q0 + 16 * wave - 1023 - t0;
    const int niHiR = relHi >> 4;
    const int niHi = (niHiR > 3) ? 3 : niHiR;            // negative => skip all
    int niLo = relLo >> 4; if (niLo < 0) niLo = 0;
    const int ktHiR = relHi >> 5;
    const int ktHi = (ktHiR > 1) ? 1 : ktHiR;
    int ktLo = relLo >> 5; if (ktLo < 0) ktLo = 0;

    float pv[4][4];
#pragma unroll
    for (int ni = 0; ni < 4; ni++) {
      if (ni < niLo || ni > niHi) {
        pv[ni][0] = pv[ni][1] = pv[ni][2] = pv[ni][3] = 0.0f;
        continue;
      }
      floatx4 sAcc = zero;
#pragma unroll
      for (int kt = 0; kt < 8; kt++) {
        short8 bk = *(const short8*)(&Ks[(ni * 16 + lane15) * 264 + kt * 32 + quad * 8]);
        sAcc = __builtin_amdgcn_mfma_f32_16x16x32_bf16(aq[kt], bk, sAcc, 0, 0, 0);
      }
#pragma unroll
      for (int r = 0; r < 4; r++) {
        // s = 50*tanh(raw/16/50) via exp+rcp; p = exp(s) (fixed base, exact)
        float x = sAcc[r] * 0.00125f;
        float ax = __builtin_fabsf(x);
        float e2 = __expf(ax + ax);
        float t = 1.0f - 2.0f * __builtin_amdgcn_rcpf(e2 + 1.0f);
        float sv = copysignf(t, x) * 50.0f;
        int i_ = iRow + r;
        int j_ = t0 + ni * 16 + lane15;
        bool ok = (j_ <= i_) && (i_ - j_ < 1024);
        pv[ni][r] = ok ? __expf(sv) : 0.0f;
      }
    }
#pragma unroll
    for (int r = 0; r < 4; r++)
      lR[r] += pv[0][r] + pv[1][r] + pv[2][r] + pv[3][r];

#pragma unroll
    for (int ni = 0; ni < 4; ni++)
#pragma unroll
      for (int r = 0; r < 4; r++)
        Ps[wave][(quad * 4 + r) * 72 + ni * 16 + lane15] = f2bf(pv[ni][r]);
    __syncthreads();  // Ps visible (Vs already staged)

#pragma unroll
    for (int ktile = 0; ktile < 2; ktile++) {
      if (ktile < ktLo || ktile > ktHi) continue;
      short8 ap = *(const short8*)(&Ps[wave][lane15 * 72 + ktile * 32 + quad * 8]);
#pragma unroll
      for (int ni = 0; ni < 16; ni++) {
        short8 bv = *(const short8*)(&Vs[(ni * 16 + lane15) * 72 + ktile * 32 + quad * 8]);
        accO[ni] = __builtin_amdgcn_mfma_f32_16x16x32_bf16(ap, bv, accO[ni], 0, 0, 0);
      }
    }
    __syncthreads();  // PV reads done before next-tile staging overwrites
  }

#pragma unroll
  for (int r = 0; r < 4; r++) {
    float l = lR[r];
    l += __shfl_xor(l, 1);
    l += __shfl_xor(l, 2);
    l += __shfl_xor(l, 4);
    l += __shfl_xor(l, 8);
    float invl = 1.0f / l;
    u16* orow = aout + (size_t)(q0 + wave * 16 + quad * 4 + r) * 4096 + h * 256;
#pragma unroll
    for (int ni = 0; ni < 16; ni++)
      orow[ni * 16 + lane15] = f2bf(accO[ni][r] * invl);
  }
}

// ---------------------------------------------------------------------------
extern "C" void kernel_launch(void* const* d_in, const int* in_sizes, int n_in,
                              void* d_out, int out_size, void* d_ws, size_t ws_size,
                              hipStream_t stream)
{
  const void* hidden = d_in[0];
  const void* w_qkv  = d_in[1];
  const void* w_o    = d_in[2];
  const void* q_w    = d_in[3];
  const void* k_w    = d_in[4];
  const void* cosb   = d_in[5];
  const void* sinb   = d_in[6];

  char* ws = (char*)d_ws;
  int* flag = (int*)ws;                                   ws += 256;
  u16* qkv  = (u16*)ws;  ws += (size_t)2048 * 8192 * 2;
  u16* vT   = (u16*)ws;  ws += (size_t)8 * 256 * 2048 * 2;
  u16* aout = (u16*)ws;  ws += (size_t)2048 * 4096 * 2;
  u16* hb   = (u16*)ws;  ws += (size_t)2048 * 3584 * 2;
  u16* wT   = (u16*)ws;

  probe_dtype_kernel<<<1, 256, 0, stream>>>(hidden, flag);
  convert_dyn_kernel<<<3584, 256, 0, stream>>>(hidden, hb, (size_t)2048 * 3584, flag);
  transpose_dyn_kernel<<<dim3(128, 56), 256, 0, stream>>>(w_qkv, wT, 3584, 8192, flag);
  gemm8p_kernel<<<dim3(32, 8), 512, 0, stream>>>(hidden, hb, wT, qkv, 2048, 8192, 3584, flag);
  normrope_kernel<<<dim3(2048, 6), 256, 0, stream>>>(qkv, q_w, k_w, cosb, sinb, flag);
  transpose_dyn_kernel<<<dim3(56, 64), 256, 0, stream>>>(w_o, wT, 4096, 3584, flag);
  vtrans_kernel<<<dim3(32, 4, 8), 256, 0, stream>>>(qkv, vT);
  attn_kernel<<<dim3(16, 16), 512, 0, stream>>>(qkv, vT, aout);
  gemm8pn_kernel<<<dim3(14, 16), 512, 0, stream>>>(aout, wT, d_out, 2048, 3584, 4096, flag, 1);
}